// Round 18
// baseline (156.209 us; speedup 1.0000x reference)
//
#include <hip/hip_runtime.h>
#include <stdint.h>

// Problem constants (fixed by setup_inputs)
#define B_SZ 2048          // batch
#define D_SZ 2047          // state dim
#define KD   2048          // D+1 == hash_size
#define K_SZ 4096          // input_length (rows of A)
#define TABLE_MASK ((1u << 22) - 1)
#define MARGIN 0.12f       // fp16 dot error rms ~0.013 -> 9 sigma (R7-R16-validated)

#define BM 128             // batch tile
#define BN 64              // k tile
#define BK 32              // inner-dim step (== MFMA K)
#define NTILES (KD / BK)   // 64
#define DCAP 3072          // per-block LDS defer staging capacity (12KB of lds[0])

typedef __attribute__((ext_vector_type(8))) _Float16 half8;
typedef __attribute__((ext_vector_type(4))) float f32x4;
typedef unsigned short ushort_t;

__device__ __forceinline__ void gl_lds16(const void* g, void* l) {
    __builtin_amdgcn_global_load_lds(
        (const __attribute__((address_space(1))) unsigned int*)g,
        (__attribute__((address_space(3))) unsigned int*)l, 16, 0, 0);
}

#define BAR()  asm volatile("s_barrier" ::: "memory")
#define VM0()  asm volatile("s_waitcnt vmcnt(0)" ::: "memory")

// ---------------------------------------------------------------------------
// Pass 0 (R8/R16-proven): f32 -> fp16 planes, 16B-chunk XOR swizzle pre-baked
// into the global layout: within each 32-d group g of row r, stored slot s
// holds logical chunk s ^ ((r>>1)&3). Also zero-inits hash_acc + defer_cnt.
// ---------------------------------------------------------------------------
__global__ __launch_bounds__(256)
void opiq_split16b(const float* __restrict__ states,
                   const float* __restrict__ actions,
                   const float* __restrict__ A,
                   ushort_t* __restrict__ Sh, ushort_t* __restrict__ Ah,
                   unsigned int* __restrict__ hash_acc)
{
    const int CS = 524288;                 // S chunks: 2048 rows * 256
    const int CT = 1572864;                // + A chunks: 4096 rows * 256
    const int i = blockIdx.x * 256 + threadIdx.x;
    if (i < B_SZ + 1) hash_acc[i] = 0u;    // hash_acc[0..B_SZ) + defer_cnt
    if (i >= CT) return;
    const bool isS = (i < CS);
    const int c    = isS ? i : (i - CS);
    const int slot = c & 3;                // stored 16B slot within 32-d group
    const int g    = (c >> 2) & 63;        // 32-d group
    const int row  = c >> 8;               // S: 0..2047, A: 0..4095
    const int key  = (row >> 1) & 3;
    const int dbase = g * 32 + ((slot ^ key) << 3);   // inverse swizzle

    float v[8];
    if (isS) {
#pragma unroll
        for (int e = 0; e < 8; ++e) {
            const int d = dbase + e;
            v[e] = (d == D_SZ) ? actions[row] : states[(size_t)row * D_SZ + d];
        }
    } else {
        const float4 a0 = *reinterpret_cast<const float4*>(&A[(size_t)row * KD + dbase]);
        const float4 a1 = *reinterpret_cast<const float4*>(&A[(size_t)row * KD + dbase + 4]);
        v[0]=a0.x; v[1]=a0.y; v[2]=a0.z; v[3]=a0.w;
        v[4]=a1.x; v[5]=a1.y; v[6]=a1.z; v[7]=a1.w;
    }
    half8 h;
#pragma unroll
    for (int e = 0; e < 8; ++e) h[e] = (_Float16)v[e];   // v_cvt_f16_f32, RN
    ushort_t* dst = isS ? Sh : Ah;
    *reinterpret_cast<half8*>(&dst[(size_t)c * 8]) = h;
}

// ---------------------------------------------------------------------------
// Main GEMM (R10-proven, 82us in-dispatch): 128x64 tile, 256 threads
// (4 waves, 2M x 2N, wave tile 64x32), BK=32, fp16 MFMA. 2-buffer VM0 drain
// pipeline, 24KB LDS, grid 1024 = 4 blocks/CU (16 waves/CU latency hiding).
// Epilogue: sign -> hash with per-block LDS defer aggregation (R8-proven).
// ---------------------------------------------------------------------------
__global__ __launch_bounds__(256)
void opiq_gemm_f16d(const ushort_t* __restrict__ Sh, const ushort_t* __restrict__ Ah,
                    const float* __restrict__ bvec,
                    const int* __restrict__ hash_coeffs,
                    unsigned int* __restrict__ hash_acc,
                    unsigned int* __restrict__ defer_cnt,
                    unsigned int* __restrict__ defer_list,
                    unsigned int defer_cap)
{
    // per buffer (ushorts): S[128][32] @0 (8KB), A[64][32] @4096 (4KB)
    __shared__ __align__(16) ushort_t lds[2][6144];   // 24 KB
    __shared__ unsigned int dcnt, dbase;

    const int tid  = threadIdx.x;
    const int lane = tid & 63;
    const int wid  = tid >> 6;          // 4 waves: 2(M) x 2(N)
    const int wj   = wid >> 1;
    const int wk   = wid & 1;
    const int l15  = lane & 15;
    const int lq   = lane >> 4;

    // XCD swizzle (1024 % 8 == 0, bijective)
    const int bid = blockIdx.x;
    const int swz = (bid & 7) * 128 + (bid >> 3);
    const int bx  = swz >> 4;           // [0,64) k-tile
    const int by  = swz & 15;           // [0,16) j-tile
    const int j0  = by * BM;
    const int k0  = bx * BN;

    // staging: S tile = 512 chunks (2/thread), A tile = 256 chunks (1/thread)
    // chunk c: row = c>>2, stored slot = c&3; LDS dest = c*16B (linear)
    const int sr = tid >> 2;            // 0..63
    const int ss = (tid & 3) * 8;       // stored 16B slot, ushort offset
    const ushort_t* pS0 = Sh + (size_t)(j0 + sr) * KD + ss;
    const ushort_t* pS1 = Sh + (size_t)(j0 + 64 + sr) * KD + ss;
    const ushort_t* pA0 = Ah + (size_t)(k0 + sr) * KD + ss;
    const int dS0 = tid * 8;
    const int dS1 = (tid + 256) * 8;
    const int dA0 = 4096 + tid * 8;

    auto STAGE = [&](int t, int s) {
        const int o = t * BK;           // ushort offset along d
        gl_lds16(pS0 + o, &lds[s][dS0]);
        gl_lds16(pS1 + o, &lds[s][dS1]);
        gl_lds16(pA0 + o, &lds[s][dA0]);
    };

    f32x4 acc[4][2];
#pragma unroll
    for (int m = 0; m < 4; ++m)
#pragma unroll
        for (int n = 0; n < 2; ++n) acc[m][n] = (f32x4){0.f, 0.f, 0.f, 0.f};

    const int frow = l15;
    const int col  = (lq ^ ((frow >> 1) & 3)) * 8;   // R3/R8/R10-proven, conflict-free

    auto do_tile = [&](const ushort_t* lb) {
        half8 sf[4], af[2];
#pragma unroll
        for (int m = 0; m < 4; ++m)
            sf[m] = *reinterpret_cast<const half8*>(
                &lb[(wj * 64 + m * 16 + frow) * BK + col]);
#pragma unroll
        for (int n = 0; n < 2; ++n)
            af[n] = *reinterpret_cast<const half8*>(
                &lb[4096 + (wk * 32 + n * 16 + frow) * BK + col]);
#pragma unroll
        for (int n = 0; n < 2; ++n)
#pragma unroll
            for (int m = 0; m < 4; ++m)
                acc[m][n] = __builtin_amdgcn_mfma_f32_16x16x32_f16(
                    sf[m], af[n], acc[m][n], 0, 0, 0);
    };

    // prologue: tile 0 staged and landed
    STAGE(0, 0);
    VM0();
    BAR();

#pragma unroll 1
    for (int t = 0; t < NTILES; ++t) {
        const int cur = t & 1;
        if (t < NTILES - 1) STAGE(t + 1, cur ^ 1);
        do_tile(lds[cur]);
        if (t < NTILES - 1) {
            VM0();                      // tile t+1's 3 loads landed
            BAR();                      // all waves see them; cur buffer free
        }
    }

    // ---- epilogue: sign -> hash; defers staged in LDS (reuse staging buffers)
    unsigned int* dbuf = reinterpret_cast<unsigned int*>(&lds[0][0]);
    __syncthreads();                     // all LDS reads of the loop are done
    if (tid == 0) dcnt = 0;
    __syncthreads();

#pragma unroll
    for (int m = 0; m < 4; ++m) {
#pragma unroll
        for (int r = 0; r < 4; ++r) {
            const int j = j0 + wj * 64 + m * 16 + lq * 4 + r;
            const float bj = bvec[j];
            unsigned int sum = 0;
#pragma unroll
            for (int n = 0; n < 2; ++n) {
                const int k = k0 + wk * 32 + n * 16 + l15;
                const float x = acc[m][n][r] + bj;
                if (__builtin_fabsf(x) <= MARGIN) {
                    const unsigned int ent = ((unsigned int)j << 12) | (unsigned int)k;
                    unsigned int slot = atomicAdd(&dcnt, 1u);
                    if (slot < DCAP) {
                        dbuf[slot] = ent;
                    } else {                       // overflow safety: direct global
                        unsigned int gs = atomicAdd(defer_cnt, 1u);
                        if (gs < defer_cap) defer_list[gs] = ent;
                    }
                } else if (x > 0.0f) {
                    sum += (unsigned int)hash_coeffs[k];
                }
            }
            sum += (unsigned int)__shfl_xor((int)sum, 1);
            sum += (unsigned int)__shfl_xor((int)sum, 2);
            sum += (unsigned int)__shfl_xor((int)sum, 4);
            sum += (unsigned int)__shfl_xor((int)sum, 8);
            if (l15 == 0) atomicAdd(&hash_acc[j], sum);
        }
    }

    __syncthreads();
    if (tid == 0) {
        unsigned int n = dcnt > DCAP ? DCAP : dcnt;
        dbase = n ? atomicAdd(defer_cnt, n) : 0u;
    }
    __syncthreads();
    {
        const unsigned int n = dcnt > DCAP ? DCAP : dcnt;
        for (unsigned int i = tid; i < n; i += 256) {
            const unsigned int s = dbase + i;
            if (s < defer_cap) defer_list[s] = dbuf[i];
        }
    }
}

// ---------------------------------------------------------------------------
// DEEP FALLBACK: exact fp64 (R0-proven), needs only hash_acc.
// ---------------------------------------------------------------------------
__global__ __launch_bounds__(256)
void opiq_gemm_f64(const float* __restrict__ states,
                   const float* __restrict__ actions,
                   const float* __restrict__ A,
                   const float* __restrict__ bvec,
                   const int* __restrict__ hash_coeffs,
                   unsigned int* __restrict__ hash_acc)
{
    __shared__ float Slds[64][33];
    __shared__ float Alds[64][33];
    const int tid = threadIdx.x;
    const int tx = tid & 15;
    const int ty = tid >> 4;
    const int j0 = blockIdx.y * 64;
    const int k0 = blockIdx.x * 64;
    double acc[4][4];
#pragma unroll
    for (int i = 0; i < 4; ++i)
#pragma unroll
        for (int jj = 0; jj < 4; ++jj) acc[i][jj] = 0.0;
    for (int d0 = 0; d0 < KD; d0 += 32) {
#pragma unroll
        for (int t = 0; t < 8; ++t) {
            int flat = t * 256 + tid;
            int r = flat >> 5, c = flat & 31;
            int d = d0 + c;
            Slds[r][c] = (d == D_SZ) ? actions[j0 + r] : states[(size_t)(j0 + r) * D_SZ + d];
            Alds[r][c] = A[(size_t)(k0 + r) * KD + d];
        }
        __syncthreads();
#pragma unroll
        for (int dd = 0; dd < 32; ++dd) {
            double s[4], a[4];
#pragma unroll
            for (int i = 0; i < 4; ++i) s[i] = (double)Slds[ty * 4 + i][dd];
#pragma unroll
            for (int jj = 0; jj < 4; ++jj) a[jj] = (double)Alds[tx * 4 + jj][dd];
#pragma unroll
            for (int i = 0; i < 4; ++i)
#pragma unroll
                for (int jj = 0; jj < 4; ++jj)
                    acc[i][jj] = fma(s[i], a[jj], acc[i][jj]);
        }
        __syncthreads();
    }
#pragma unroll
    for (int i = 0; i < 4; ++i) {
        const int j = j0 + ty * 4 + i;
        const double bj = (double)bvec[j];
        unsigned int sum = 0;
#pragma unroll
        for (int jj = 0; jj < 4; ++jj) {
            const int k = k0 + tx * 4 + jj;
            if (acc[i][jj] + bj > 0.0) sum += (unsigned int)hash_coeffs[k];
        }
        sum += (unsigned int)__shfl_xor((int)sum, 1);
        sum += (unsigned int)__shfl_xor((int)sum, 2);
        sum += (unsigned int)__shfl_xor((int)sum, 4);
        sum += (unsigned int)__shfl_xor((int)sum, 8);
        if (tx == 0) atomicAdd(&hash_acc[j], sum);
    }
}

// Exact fp64 recompute of deferred dots; one wave per deferred (j,k) pair.
__global__ __launch_bounds__(256)
void opiq_fixup(const float* __restrict__ states,
                const float* __restrict__ actions,
                const float* __restrict__ A,
                const float* __restrict__ bvec,
                const int* __restrict__ hash_coeffs,
                unsigned int* __restrict__ hash_acc,
                const unsigned int* __restrict__ defer_cnt,
                const unsigned int* __restrict__ defer_list,
                unsigned int defer_cap)
{
    const int gtid = blockIdx.x * 256 + threadIdx.x;
    const int wave = gtid >> 6;
    const int lane = gtid & 63;
    const int n_waves = gridDim.x * 4;
    unsigned int n = *defer_cnt;
    if (n > defer_cap) n = defer_cap;
    for (unsigned int e = wave; e < n; e += n_waves) {
        const unsigned int ent = defer_list[e];
        const int j = (int)(ent >> 12);
        const int k = (int)(ent & 4095);
        double part = 0.0;
        const int dbase2 = lane * 32;
#pragma unroll 8
        for (int t = 0; t < 32; ++t) {
            const int d = dbase2 + t;
            const float sv = (d == D_SZ) ? actions[j] : states[(size_t)j * D_SZ + d];
            part = fma((double)sv, (double)A[(size_t)k * KD + d], part);
        }
#pragma unroll
        for (int m = 1; m < 64; m <<= 1)
            part += __shfl_xor(part, m);
        const double x = part + (double)bvec[j];
        if (lane == 0 && x > 0.0)
            atomicAdd(&hash_acc[j], (unsigned int)hash_coeffs[k]);
    }
}

__global__ void opiq_final(const unsigned int* __restrict__ hash_acc,
                           const int* __restrict__ count_table,
                           float* __restrict__ out)
{
    int j = blockIdx.x * 256 + threadIdx.x;
    if (j < B_SZ) {
        unsigned int idx = hash_acc[j] & TABLE_MASK;
        float c = (float)count_table[idx];
        float t = c + 1.0f;
        out[j] = 1.0f / (t * t);
    }
}

extern "C" void kernel_launch(void* const* d_in, const int* in_sizes, int n_in,
                              void* d_out, int out_size, void* d_ws, size_t ws_size,
                              hipStream_t stream) {
    const float* states      = (const float*)d_in[0];
    const float* actions     = (const float*)d_in[1];
    const float* A           = (const float*)d_in[2];
    const float* bvec        = (const float*)d_in[3];
    const int*   count_table = (const int*)d_in[4];
    const int*   hash_coeffs = (const int*)d_in[5];
    float* out = (float*)d_out;

    unsigned int* hash_acc  = (unsigned int*)d_ws;
    unsigned int* defer_cnt = hash_acc + B_SZ;

    // ws: [0,8K) hash_acc(+defer_cnt) | [16K,16K+4M) defer_list | fp16 planes (25.2MB)
    const size_t DEFER_OFF  = 16384;
    const size_t DEFER_CAP  = 1u << 20;
    const size_t PLANES_OFF = DEFER_OFF + DEFER_CAP * 4;
    const size_t S_ELEMS = (size_t)B_SZ * KD;   // 4.19M
    const size_t A_ELEMS = (size_t)K_SZ * KD;   // 8.39M
    const size_t REQ = PLANES_OFF + (S_ELEMS + A_ELEMS) * sizeof(ushort_t);

    if (ws_size >= REQ) {
        unsigned int* defer_list = (unsigned int*)((char*)d_ws + DEFER_OFF);
        ushort_t* Sh = (ushort_t*)((char*)d_ws + PLANES_OFF);
        ushort_t* Ah = Sh + S_ELEMS;

        // 4 dispatches: split (zeroes counters) -> gemm -> fixup -> final
        opiq_split16b<<<6144, 256, 0, stream>>>(states, actions, A, Sh, Ah, hash_acc);
        opiq_gemm_f16d<<<1024, 256, 0, stream>>>(Sh, Ah, bvec, hash_coeffs,
                                                 hash_acc, defer_cnt, defer_list,
                                                 (unsigned int)DEFER_CAP);
        opiq_fixup<<<256, 256, 0, stream>>>(states, actions, A, bvec, hash_coeffs,
                                            hash_acc, defer_cnt, defer_list,
                                            (unsigned int)DEFER_CAP);
    } else {
        hipMemsetAsync(d_ws, 0, B_SZ * sizeof(unsigned int), stream);
        dim3 grid(K_SZ / 64, B_SZ / 64);
        opiq_gemm_f64<<<grid, 256, 0, stream>>>(states, actions, A, bvec,
                                                hash_coeffs, hash_acc);
    }
    opiq_final<<<(B_SZ + 255) / 256, 256, 0, stream>>>(hash_acc, count_table, out);
}

// Round 19
// 149.544 us; speedup vs baseline: 1.0446x; 1.0446x over previous
//
#include <hip/hip_runtime.h>
#include <stdint.h>

// Problem constants (fixed by setup_inputs)
#define B_SZ 2048          // batch
#define D_SZ 2047          // state dim
#define KD   2048          // D+1 == hash_size
#define K_SZ 4096          // input_length (rows of A)
#define TABLE_MASK ((1u << 22) - 1)
#define MARGIN 0.12f       // fp16 dot error rms ~0.013 -> 9 sigma (R7-R17-validated)

#define BM 128             // batch tile
#define BN 128             // k tile
#define BK 32              // inner-dim step (== MFMA K)
#define NTILES (KD / BK)   // 64
#define DCAP 4096          // per-block LDS defer staging capacity

typedef __attribute__((ext_vector_type(8))) _Float16 half8;
typedef __attribute__((ext_vector_type(4))) float f32x4;
typedef unsigned short ushort_t;

__device__ __forceinline__ void gl_lds16(const void* g, void* l) {
    __builtin_amdgcn_global_load_lds(
        (const __attribute__((address_space(1))) unsigned int*)g,
        (__attribute__((address_space(3))) unsigned int*)l, 16, 0, 0);
}

#define BAR()  asm volatile("s_barrier" ::: "memory")
#define VM0()  asm volatile("s_waitcnt vmcnt(0)" ::: "memory")

// ---------------------------------------------------------------------------
// Pass 0 (R16-proven): f32 -> fp16 planes, 16B-chunk XOR swizzle pre-baked
// into the global layout: within each 32-d group g of row r, stored slot s
// holds logical chunk s ^ ((r>>1)&3). Also zero-inits hash_acc + defer_cnt.
// ---------------------------------------------------------------------------
__global__ __launch_bounds__(256)
void opiq_split16b(const float* __restrict__ states,
                   const float* __restrict__ actions,
                   const float* __restrict__ A,
                   ushort_t* __restrict__ Sh, ushort_t* __restrict__ Ah,
                   unsigned int* __restrict__ hash_acc)
{
    const int CS = 524288;                 // S chunks: 2048 rows * 256
    const int CT = 1572864;                // + A chunks: 4096 rows * 256
    const int i = blockIdx.x * 256 + threadIdx.x;
    if (i < B_SZ + 1) hash_acc[i] = 0u;    // hash_acc[0..B_SZ) + defer_cnt
    if (i >= CT) return;
    const bool isS = (i < CS);
    const int c    = isS ? i : (i - CS);
    const int slot = c & 3;                // stored 16B slot within 32-d group
    const int g    = (c >> 2) & 63;        // 32-d group
    const int row  = c >> 8;               // S: 0..2047, A: 0..4095
    const int key  = (row >> 1) & 3;
    const int dbase = g * 32 + ((slot ^ key) << 3);   // inverse swizzle

    float v[8];
    if (isS) {
#pragma unroll
        for (int e = 0; e < 8; ++e) {
            const int d = dbase + e;
            v[e] = (d == D_SZ) ? actions[row] : states[(size_t)row * D_SZ + d];
        }
    } else {
        const float4 a0 = *reinterpret_cast<const float4*>(&A[(size_t)row * KD + dbase]);
        const float4 a1 = *reinterpret_cast<const float4*>(&A[(size_t)row * KD + dbase + 4]);
        v[0]=a0.x; v[1]=a0.y; v[2]=a0.z; v[3]=a0.w;
        v[4]=a1.x; v[5]=a1.y; v[6]=a1.z; v[7]=a1.w;
    }
    half8 h;
#pragma unroll
    for (int e = 0; e < 8; ++e) h[e] = (_Float16)v[e];   // v_cvt_f16_f32, RN
    ushort_t* dst = isS ? Sh : Ah;
    *reinterpret_cast<half8*>(&dst[(size_t)c * 8]) = h;
}

// ---------------------------------------------------------------------------
// Main GEMM (R16-proven, best total 149.65us): 128x128 tile, 256 threads
// (4 waves, 2M x 2N), BK=32, fp16 MFMA. 2-buffer VM0 drain pipeline,
// 32KB LDS, grid 512. Epilogue: sign -> hash with per-block LDS defer
// aggregation.
// ---------------------------------------------------------------------------
__global__ __launch_bounds__(256)
void opiq_gemm_f16c(const ushort_t* __restrict__ Sh, const ushort_t* __restrict__ Ah,
                    const float* __restrict__ bvec,
                    const int* __restrict__ hash_coeffs,
                    unsigned int* __restrict__ hash_acc,
                    unsigned int* __restrict__ defer_cnt,
                    unsigned int* __restrict__ defer_list,
                    unsigned int defer_cap)
{
    // per buffer (ushorts): S[128][32] @0 (8KB), A[128][32] @4096 (8KB)
    __shared__ __align__(16) ushort_t lds[2][8192];   // 32 KB
    __shared__ unsigned int dcnt, dbase;

    const int tid  = threadIdx.x;
    const int lane = tid & 63;
    const int wid  = tid >> 6;          // 4 waves: 2(M) x 2(N)
    const int wj   = wid >> 1;
    const int wk   = wid & 1;
    const int l15  = lane & 15;
    const int lq   = lane >> 4;

    // XCD swizzle (512 % 8 == 0, bijective)
    const int bid = blockIdx.x;
    const int swz = (bid & 7) * 64 + (bid >> 3);
    const int bx  = swz >> 4;           // [0,32) k-tile
    const int by  = swz & 15;           // [0,16) j-tile
    const int j0  = by * BM;
    const int k0  = bx * BN;

    // staging: S tile = 512 chunks (2/thread), A tile = 512 chunks (2/thread)
    // chunk c: row = c>>2, stored slot = c&3; LDS dest = c*16B (linear)
    const int sr = tid >> 2;            // 0..63
    const int ss = (tid & 3) * 8;       // stored 16B slot, ushort offset
    const ushort_t* pS0 = Sh + (size_t)(j0 + sr) * KD + ss;
    const ushort_t* pS1 = Sh + (size_t)(j0 + 64 + sr) * KD + ss;
    const ushort_t* pA0 = Ah + (size_t)(k0 + sr) * KD + ss;
    const ushort_t* pA1 = Ah + (size_t)(k0 + 64 + sr) * KD + ss;
    const int dS0 = tid * 8,           dS1 = (tid + 256) * 8;
    const int dA0 = 4096 + tid * 8,    dA1 = 4096 + (tid + 256) * 8;

    auto STAGE = [&](int t, int s) {
        const int o = t * BK;           // ushort offset along d
        gl_lds16(pS0 + o, &lds[s][dS0]);
        gl_lds16(pS1 + o, &lds[s][dS1]);
        gl_lds16(pA0 + o, &lds[s][dA0]);
        gl_lds16(pA1 + o, &lds[s][dA1]);
    };

    f32x4 acc[4][4];
#pragma unroll
    for (int m = 0; m < 4; ++m)
#pragma unroll
        for (int n = 0; n < 4; ++n) acc[m][n] = (f32x4){0.f, 0.f, 0.f, 0.f};

    const int frow = l15;
    const int col  = (lq ^ ((frow >> 1) & 3)) * 8;   // R3/R8/R9-proven, conflict-free

    auto do_tile = [&](const ushort_t* lb) {
        half8 sf[4], af[4];
#pragma unroll
        for (int m = 0; m < 4; ++m)
            sf[m] = *reinterpret_cast<const half8*>(
                &lb[(wj * 64 + m * 16 + frow) * BK + col]);
#pragma unroll
        for (int n = 0; n < 4; ++n)
            af[n] = *reinterpret_cast<const half8*>(
                &lb[4096 + (wk * 64 + n * 16 + frow) * BK + col]);
#pragma unroll
        for (int n = 0; n < 4; ++n)
#pragma unroll
            for (int m = 0; m < 4; ++m)
                acc[m][n] = __builtin_amdgcn_mfma_f32_16x16x32_f16(
                    sf[m], af[n], acc[m][n], 0, 0, 0);
    };

    // prologue: tile 0 staged and landed
    STAGE(0, 0);
    VM0();
    BAR();

#pragma unroll 1
    for (int t = 0; t < NTILES; ++t) {
        const int cur = t & 1;
        if (t < NTILES - 1) STAGE(t + 1, cur ^ 1);
        do_tile(lds[cur]);
        if (t < NTILES - 1) {
            VM0();                      // tile t+1's 4 loads landed
            BAR();                      // all waves see them; cur buffer free
        }
    }

    // ---- epilogue: sign -> hash; defers staged in LDS (reuse staging buffers)
    unsigned int* dbuf = reinterpret_cast<unsigned int*>(&lds[0][0]);
    __syncthreads();                     // all LDS reads of the loop are done
    if (tid == 0) dcnt = 0;
    __syncthreads();

#pragma unroll
    for (int m = 0; m < 4; ++m) {
#pragma unroll
        for (int r = 0; r < 4; ++r) {
            const int j = j0 + wj * 64 + m * 16 + lq * 4 + r;
            const float bj = bvec[j];
            unsigned int sum = 0;
#pragma unroll
            for (int n = 0; n < 4; ++n) {
                const int k = k0 + wk * 64 + n * 16 + l15;
                const float x = acc[m][n][r] + bj;
                if (__builtin_fabsf(x) <= MARGIN) {
                    const unsigned int ent = ((unsigned int)j << 12) | (unsigned int)k;
                    unsigned int slot = atomicAdd(&dcnt, 1u);
                    if (slot < DCAP) {
                        dbuf[slot] = ent;
                    } else {                       // overflow safety: direct global
                        unsigned int gs = atomicAdd(defer_cnt, 1u);
                        if (gs < defer_cap) defer_list[gs] = ent;
                    }
                } else if (x > 0.0f) {
                    sum += (unsigned int)hash_coeffs[k];
                }
            }
            sum += (unsigned int)__shfl_xor((int)sum, 1);
            sum += (unsigned int)__shfl_xor((int)sum, 2);
            sum += (unsigned int)__shfl_xor((int)sum, 4);
            sum += (unsigned int)__shfl_xor((int)sum, 8);
            if (l15 == 0) atomicAdd(&hash_acc[j], sum);
        }
    }

    __syncthreads();
    if (tid == 0) {
        unsigned int n = dcnt > DCAP ? DCAP : dcnt;
        dbase = n ? atomicAdd(defer_cnt, n) : 0u;
    }
    __syncthreads();
    {
        const unsigned int n = dcnt > DCAP ? DCAP : dcnt;
        for (unsigned int i = tid; i < n; i += 256) {
            const unsigned int s = dbase + i;
            if (s < defer_cap) defer_list[s] = dbuf[i];
        }
    }
}

// ---------------------------------------------------------------------------
// DEEP FALLBACK: exact fp64 (R0-proven), needs only hash_acc.
// ---------------------------------------------------------------------------
__global__ __launch_bounds__(256)
void opiq_gemm_f64(const float* __restrict__ states,
                   const float* __restrict__ actions,
                   const float* __restrict__ A,
                   const float* __restrict__ bvec,
                   const int* __restrict__ hash_coeffs,
                   unsigned int* __restrict__ hash_acc)
{
    __shared__ float Slds[64][33];
    __shared__ float Alds[64][33];
    const int tid = threadIdx.x;
    const int tx = tid & 15;
    const int ty = tid >> 4;
    const int j0 = blockIdx.y * 64;
    const int k0 = blockIdx.x * 64;
    double acc[4][4];
#pragma unroll
    for (int i = 0; i < 4; ++i)
#pragma unroll
        for (int jj = 0; jj < 4; ++jj) acc[i][jj] = 0.0;
    for (int d0 = 0; d0 < KD; d0 += 32) {
#pragma unroll
        for (int t = 0; t < 8; ++t) {
            int flat = t * 256 + tid;
            int r = flat >> 5, c = flat & 31;
            int d = d0 + c;
            Slds[r][c] = (d == D_SZ) ? actions[j0 + r] : states[(size_t)(j0 + r) * D_SZ + d];
            Alds[r][c] = A[(size_t)(k0 + r) * KD + d];
        }
        __syncthreads();
#pragma unroll
        for (int dd = 0; dd < 32; ++dd) {
            double s[4], a[4];
#pragma unroll
            for (int i = 0; i < 4; ++i) s[i] = (double)Slds[ty * 4 + i][dd];
#pragma unroll
            for (int jj = 0; jj < 4; ++jj) a[jj] = (double)Alds[tx * 4 + jj][dd];
#pragma unroll
            for (int i = 0; i < 4; ++i)
#pragma unroll
                for (int jj = 0; jj < 4; ++jj)
                    acc[i][jj] = fma(s[i], a[jj], acc[i][jj]);
        }
        __syncthreads();
    }
#pragma unroll
    for (int i = 0; i < 4; ++i) {
        const int j = j0 + ty * 4 + i;
        const double bj = (double)bvec[j];
        unsigned int sum = 0;
#pragma unroll
        for (int jj = 0; jj < 4; ++jj) {
            const int k = k0 + tx * 4 + jj;
            if (acc[i][jj] + bj > 0.0) sum += (unsigned int)hash_coeffs[k];
        }
        sum += (unsigned int)__shfl_xor((int)sum, 1);
        sum += (unsigned int)__shfl_xor((int)sum, 2);
        sum += (unsigned int)__shfl_xor((int)sum, 4);
        sum += (unsigned int)__shfl_xor((int)sum, 8);
        if (tx == 0) atomicAdd(&hash_acc[j], sum);
    }
}

// Exact fp64 recompute of deferred dots; one wave per deferred (j,k) pair.
__global__ __launch_bounds__(256)
void opiq_fixup(const float* __restrict__ states,
                const float* __restrict__ actions,
                const float* __restrict__ A,
                const float* __restrict__ bvec,
                const int* __restrict__ hash_coeffs,
                unsigned int* __restrict__ hash_acc,
                const unsigned int* __restrict__ defer_cnt,
                const unsigned int* __restrict__ defer_list,
                unsigned int defer_cap)
{
    const int gtid = blockIdx.x * 256 + threadIdx.x;
    const int wave = gtid >> 6;
    const int lane = gtid & 63;
    const int n_waves = gridDim.x * 4;
    unsigned int n = *defer_cnt;
    if (n > defer_cap) n = defer_cap;
    for (unsigned int e = wave; e < n; e += n_waves) {
        const unsigned int ent = defer_list[e];
        const int j = (int)(ent >> 12);
        const int k = (int)(ent & 4095);
        double part = 0.0;
        const int dbase2 = lane * 32;
#pragma unroll 8
        for (int t = 0; t < 32; ++t) {
            const int d = dbase2 + t;
            const float sv = (d == D_SZ) ? actions[j] : states[(size_t)j * D_SZ + d];
            part = fma((double)sv, (double)A[(size_t)k * KD + d], part);
        }
#pragma unroll
        for (int m = 1; m < 64; m <<= 1)
            part += __shfl_xor(part, m);
        const double x = part + (double)bvec[j];
        if (lane == 0 && x > 0.0)
            atomicAdd(&hash_acc[j], (unsigned int)hash_coeffs[k]);
    }
}

__global__ void opiq_final(const unsigned int* __restrict__ hash_acc,
                           const int* __restrict__ count_table,
                           float* __restrict__ out)
{
    int j = blockIdx.x * 256 + threadIdx.x;
    if (j < B_SZ) {
        unsigned int idx = hash_acc[j] & TABLE_MASK;
        float c = (float)count_table[idx];
        float t = c + 1.0f;
        out[j] = 1.0f / (t * t);
    }
}

extern "C" void kernel_launch(void* const* d_in, const int* in_sizes, int n_in,
                              void* d_out, int out_size, void* d_ws, size_t ws_size,
                              hipStream_t stream) {
    const float* states      = (const float*)d_in[0];
    const float* actions     = (const float*)d_in[1];
    const float* A           = (const float*)d_in[2];
    const float* bvec        = (const float*)d_in[3];
    const int*   count_table = (const int*)d_in[4];
    const int*   hash_coeffs = (const int*)d_in[5];
    float* out = (float*)d_out;

    unsigned int* hash_acc  = (unsigned int*)d_ws;
    unsigned int* defer_cnt = hash_acc + B_SZ;

    // ws: [0,8K) hash_acc(+defer_cnt) | [16K,16K+4M) defer_list | fp16 planes (25.2MB)
    const size_t DEFER_OFF  = 16384;
    const size_t DEFER_CAP  = 1u << 20;
    const size_t PLANES_OFF = DEFER_OFF + DEFER_CAP * 4;
    const size_t S_ELEMS = (size_t)B_SZ * KD;   // 4.19M
    const size_t A_ELEMS = (size_t)K_SZ * KD;   // 8.39M
    const size_t REQ = PLANES_OFF + (S_ELEMS + A_ELEMS) * sizeof(ushort_t);

    if (ws_size >= REQ) {
        unsigned int* defer_list = (unsigned int*)((char*)d_ws + DEFER_OFF);
        ushort_t* Sh = (ushort_t*)((char*)d_ws + PLANES_OFF);
        ushort_t* Ah = Sh + S_ELEMS;

        // 4 dispatches: split (zeroes counters) -> gemm -> fixup -> final
        opiq_split16b<<<6144, 256, 0, stream>>>(states, actions, A, Sh, Ah, hash_acc);
        opiq_gemm_f16c<<<512, 256, 0, stream>>>(Sh, Ah, bvec, hash_coeffs,
                                                hash_acc, defer_cnt, defer_list,
                                                (unsigned int)DEFER_CAP);
        opiq_fixup<<<256, 256, 0, stream>>>(states, actions, A, bvec, hash_coeffs,
                                            hash_acc, defer_cnt, defer_list,
                                            (unsigned int)DEFER_CAP);
    } else {
        hipMemsetAsync(d_ws, 0, B_SZ * sizeof(unsigned int), stream);
        dim3 grid(K_SZ / 64, B_SZ / 64);
        opiq_gemm_f64<<<grid, 256, 0, stream>>>(states, actions, A, bvec,
                                                hash_coeffs, hash_acc);
    }
    opiq_final<<<(B_SZ + 255) / 256, 256, 0, stream>>>(hash_acc, count_table, out);
}